// Round 3
// baseline (371.212 us; speedup 1.0000x reference)
//
#include <hip/hip_runtime.h>

// MaxUnpooling2D, OUTPUT-MAJOR gather with grid-stride loop.
// B=16, H=W=64, C=256, OH=OW=128, 2x2 windows.
//
// R2 lesson: input-major gather (each thread scatters 4 window positions,
// two 2KiB runs 128KiB apart per wave, 6 VMEM ops then exit) ran far below
// copy bandwidth; store cache policy (NT vs plain) made zero difference.
// This version makes the store stream exactly fill-shaped: threads iterate
// output quads linearly, every wave store is part of one dense contiguous
// stream, threads are long-lived (32 iterations each).
//
// out[b,oh,ow,c] = (mask[b,oh/2,ow/2,c] == flat(oh,ow,c)) ? updates[...] : 0
// Each input quad is read by 4 output quads; the reuse window per grid sweep
// is ~4 MiB -> L2-resident, so HBM traffic stays 64+64 MiB reads.
// Total HBM: 128 MiB read + 256 MiB write = 384 MiB.

constexpr int B = 16;
constexpr int H = 64, W = 64, C = 256;
constexpr int OH = 2 * H, OW = 2 * W;
constexpr int N_OUT_QUADS = B * OH * OW * (C / 4);   // 16,777,216
constexpr int GRID  = 2048;                           // 8 blocks/CU, grid-stride
constexpr int BLOCK = 256;

typedef float f32x4 __attribute__((ext_vector_type(4)));
typedef int   i32x4 __attribute__((ext_vector_type(4)));

__global__ __launch_bounds__(BLOCK) void unpool_outmajor_kernel(
    const f32x4* __restrict__ upd4,
    const i32x4* __restrict__ mask4,
    f32x4* __restrict__ out4) {
    const int stride = GRID * BLOCK;                  // 524,288 quads / sweep
    int q = blockIdx.x * BLOCK + threadIdx.x;

    // 32 sweeps exactly: N_OUT_QUADS / stride == 32, no tail.
#pragma unroll 1
    for (int it = 0; it < N_OUT_QUADS / stride; ++it, q += stride) {
        // q -> (b, oh, ow, c0/4) in [B,OH,OW,C] layout
        int cq = q & 63;              // c0/4
        int ow = (q >> 6) & 127;
        int oh = (q >> 13) & 127;
        int b  = q >> 20;

        // corresponding input quad (b, oh/2, ow/2, c0/4)
        int iq = (b << 18) + ((oh >> 1) << 12) + ((ow >> 1) << 6) + cq;
        i32x4 m = mask4[iq];
        f32x4 u = upd4[iq];

        // per-batch flat output index of this quad's first element
        int flat = (oh << 15) + (ow << 8) + (cq << 2);
        f32x4 r;
        r.x = (m.x == flat)     ? u.x : 0.0f;
        r.y = (m.y == flat + 1) ? u.y : 0.0f;
        r.z = (m.z == flat + 2) ? u.z : 0.0f;
        r.w = (m.w == flat + 3) ? u.w : 0.0f;
        out4[q] = r;                  // dense linear store stream
    }
}

extern "C" void kernel_launch(void* const* d_in, const int* in_sizes, int n_in,
                              void* d_out, int out_size, void* d_ws, size_t ws_size,
                              hipStream_t stream) {
    const f32x4* upd4  = (const f32x4*)d_in[0];
    const i32x4* mask4 = (const i32x4*)d_in[1];
    f32x4*       out4  = (f32x4*)d_out;

    // No memset: every output quad is written exactly once by the kernel.
    unpool_outmajor_kernel<<<GRID, BLOCK, 0, stream>>>(upd4, mask4, out4);
}

// Round 4
// 356.932 us; speedup vs baseline: 1.0400x; 1.0400x over previous
//
#include <hip/hip_runtime.h>

// MaxUnpooling2D: back to the empirically-best structure (R0: memset + scatter),
// with two fixes:
//  1. Memset EXACTLY the output size (268,435,456 bytes, computed from shape,
//     no dependence on out_size units). R0 used out_size*sizeof(float), which
//     is 4x too much if out_size is in bytes (1 GiB fill = ~124 us wasted).
//  2. Vectorized input loads (i32x4 mask + f32x4 updates per thread), scalar
//     mask-driven stores (correct for ANY argmax mask, no structure assumed).
//
// Traffic: memset 256 MiB (fill rate ~6.5 TB/s = ~41 us) +
//          scatter reads 128 MiB + writes 64 MiB (~30 us) = ~71 us of our work.
// Cross-round evidence (R0-R3): timed window carries ~280-300 us of fixed
// harness poison-fill cost; among our variants, scatter+memset (192 MiB kernel
// traffic) empirically beats the 384 MiB single-pass gather.

constexpr int B = 16;
constexpr int H = 64, W = 64, C = 256;
constexpr int OH = 2 * H, OW = 2 * W;
constexpr long long OUT_PER_BATCH = (long long)OH * OW * C;          // 4,194,304
constexpr size_t OUT_BYTES = (size_t)B * OUT_PER_BATCH * sizeof(float); // 256 MiB
constexpr int N_QUADS = B * H * W * (C / 4);                         // 4,194,304

typedef float f32x4 __attribute__((ext_vector_type(4)));
typedef int   i32x4 __attribute__((ext_vector_type(4)));

__global__ __launch_bounds__(256) void unpool_scatter4_kernel(
    const f32x4* __restrict__ upd4,
    const i32x4* __restrict__ mask4,
    float* __restrict__ out) {
    int i = blockIdx.x * blockDim.x + threadIdx.x;   // quad index, exact grid
    int b = i >> 18;                                 // i / (H*W*C/4)

    i32x4 m = mask4[i];                              // 16B vector load
    f32x4 u = upd4[i];                               // 16B vector load

    float* obase = out + (long long)b * OUT_PER_BATCH;
    // Mask-driven scalar stores: correct for any valid argmax mask.
    // For the actual data (per-window positions), a wave's 4 store
    // instructions cover one contiguous 1 KiB output run -> full lines.
    obase[m.x] = u.x;
    obase[m.y] = u.y;
    obase[m.z] = u.z;
    obase[m.w] = u.w;
}

extern "C" void kernel_launch(void* const* d_in, const int* in_sizes, int n_in,
                              void* d_out, int out_size, void* d_ws, size_t ws_size,
                              hipStream_t stream) {
    const f32x4* upd4  = (const f32x4*)d_in[0];
    const i32x4* mask4 = (const i32x4*)d_in[1];
    float*       out   = (float*)d_out;

    // Zero exactly the output (poisoned to 0xAA before every timed launch).
    hipMemsetAsync(out, 0, OUT_BYTES, stream);

    const int block = 256;
    const int grid  = N_QUADS / block;               // 16384 blocks, exact
    unpool_scatter4_kernel<<<grid, block, 0, stream>>>(upd4, mask4, out);
}